// Round 1
// 871.130 us; speedup vs baseline: 1.0750x; 1.0750x over previous
//
#include <hip/hip_runtime.h>

// ---------------------------------------------------------------------------
// BlockSparseMoE: T=4096 tokens, HID=1024, FFN=4096, E=8, top-2, fp32 in/out.
// route (fp32) -> permute tokens into 256-aligned expert segments -> bf16 MFMA
// grouped GEMMs with global_load_lds(16B) staging.
// R4: k5 rewritten to 256x128 dual-B 8-wave block, BK=64, 128KiB dbuf LDS,
// 4-phase/K-tile interleave with counted vmcnt (T3+T4), setprio around MFMA
// (T5), XOR bank swizzle kept (T2), XCD-aware block swizzle (T1) on k5+k6.
// Segments 256-aligned; k6 keeps 128-row tiles (subset of k5 coverage).
// ---------------------------------------------------------------------------

#define NTOK 4096
#define HID  1024
#define FFN  4096
#define NE   8
#define CAP  10240    // 256-aligned slots: 8192 + 8*255 = 10232 <= 10240
#define MAXT 72       // 128-row tiles (k6): sum ceil(c/128) <= 71
#define MAXT256 40    // 256-row tiles (k5): sum ceil(c/256) <= 39
#define NKT5 16       // HID/64 K-tiles in k5

typedef __bf16 bf16x8 __attribute__((ext_vector_type(8)));
typedef float  f32x4  __attribute__((ext_vector_type(4)));

typedef __attribute__((address_space(3))) unsigned int       lds_uint;
typedef const __attribute__((address_space(1))) unsigned int glob_uint;

__device__ __forceinline__ unsigned short f2bf(float f) {
  union { float f; unsigned u; } v; v.f = f;
  return (unsigned short)((v.u + 0x7FFFu + ((v.u >> 16) & 1u)) >> 16); // RNE
}

__device__ __forceinline__ void gload16(const void* g, void* l) {
  __builtin_amdgcn_global_load_lds((glob_uint*)g, (lds_uint*)l, 16, 0, 0);
}

// ---- K0: zero out, convert x -> bf16, zero expert counts --------------------
__global__ void k0_zero_cvt(const float* __restrict__ x,
                            unsigned short* __restrict__ xbf,
                            float* __restrict__ out,
                            int* __restrict__ counts) {
  int i = blockIdx.x * 256 + threadIdx.x;
  const float4* x4 = (const float4*)x;
  float4 v = x4[i];
  uint2 p;
  p.x = (unsigned)f2bf(v.x) | ((unsigned)f2bf(v.y) << 16);
  p.y = (unsigned)f2bf(v.z) | ((unsigned)f2bf(v.w) << 16);
  ((uint2*)xbf)[i] = p;
  ((float4*)out)[i] = make_float4(0.f, 0.f, 0.f, 0.f);
  if (i < NE) counts[i] = 0;
}

// ---- K1: vectorized 64x64 transpose + fp32->bf16 ----------------------------
__global__ __launch_bounds__(256) void k1_transpose(
    const float* __restrict__ s0, unsigned short* __restrict__ d0,
    const float* __restrict__ s1, unsigned short* __restrict__ d1,
    int Rfull, int Cfull, int rg0, int cg0, int RW, int CW) {
  __shared__ unsigned short tile[64 * 72];   // pitch 72 (144B): breaks read conflicts
  int z = blockIdx.z;
  const float* src = (z < 8 ? s0 : s1) + (size_t)(z & 7) * Rfull * Cfull;
  unsigned short* dst = (z < 8 ? d0 : d1) + (size_t)(z & 7) * RW * CW;
  int c0 = blockIdx.x * 64;   // local col tile
  int r0 = blockIdx.y * 64;   // local row tile
  int t = threadIdx.x;
  int q = t >> 4, p = t & 15;

  const float4* s4 = (const float4*)(src + (size_t)(rg0 + r0 + 4 * q) * Cfull
                                     + cg0 + c0) + p;
  unsigned short v[4][4];
#pragma unroll
  for (int u = 0; u < 4; u++) {
    float4 xv = s4[(size_t)u * (Cfull >> 2)];
    v[u][0] = f2bf(xv.x); v[u][1] = f2bf(xv.y);
    v[u][2] = f2bf(xv.z); v[u][3] = f2bf(xv.w);
  }
#pragma unroll
  for (int j = 0; j < 4; j++) {
    ushort4 w = make_ushort4(v[0][j], v[1][j], v[2][j], v[3][j]);
    *(ushort4*)&tile[(4 * p + j) * 72 + 4 * q] = w;
  }
  __syncthreads();
  int b = t & 7;
#pragma unroll
  for (int vi = 0; vi < 2; vi++) {
    int c = (t >> 3) + 32 * vi;                       // 0..63
    uint4 w = *(const uint4*)&tile[c * 72 + 8 * b];
    *(uint4*)(dst + (size_t)(c0 + c) * RW + r0 + 8 * b) = w;
  }
}

// ---- K2: router, one wave per token ----------------------------------------
__global__ void k2_router(const float* __restrict__ x,
                          const float* __restrict__ gw,
                          const float* __restrict__ gb,
                          int* __restrict__ topi, float* __restrict__ topw,
                          int* __restrict__ counts) {
  int wid = threadIdx.x >> 6, lane = threadIdx.x & 63;
  int t = blockIdx.x * 4 + wid;
  const float4* x4 = (const float4*)(x + (size_t)t * HID);
  const float4* g4 = (const float4*)gw;
  float acc[8];
#pragma unroll
  for (int e = 0; e < 8; e++) acc[e] = 0.f;
#pragma unroll
  for (int i = 0; i < 4; i++) {
    float4 xv = x4[i * 64 + lane];
    int dbase = (i * 64 + lane) * 4;
    float xs[4] = {xv.x, xv.y, xv.z, xv.w};
#pragma unroll
    for (int j = 0; j < 4; j++) {
      float4 ga  = g4[(dbase + j) * 2];
      float4 gbv = g4[(dbase + j) * 2 + 1];
      acc[0] += xs[j] * ga.x;  acc[1] += xs[j] * ga.y;
      acc[2] += xs[j] * ga.z;  acc[3] += xs[j] * ga.w;
      acc[4] += xs[j] * gbv.x; acc[5] += xs[j] * gbv.y;
      acc[6] += xs[j] * gbv.z; acc[7] += xs[j] * gbv.w;
    }
  }
#pragma unroll
  for (int e = 0; e < 8; e++)
#pragma unroll
    for (int m = 1; m < 64; m <<= 1) acc[e] += __shfl_xor(acc[e], m);
  if (lane == 0) {
    float lg[8];
#pragma unroll
    for (int e = 0; e < 8; e++) lg[e] = acc[e] + gb[e];
    int i0 = 0; float m0 = lg[0];
#pragma unroll
    for (int e = 1; e < 8; e++) if (lg[e] > m0) { m0 = lg[e]; i0 = e; }
    int i1 = -1; float m1 = -1e30f;
#pragma unroll
    for (int e = 0; e < 8; e++) if (e != i0 && lg[e] > m1) { m1 = lg[e]; i1 = e; }
    float w0 = 1.f / (1.f + __expf(m1 - m0));   // == p0/(p0+p1) renormalized
    topi[2 * t] = i0; topi[2 * t + 1] = i1;
    topw[2 * t] = w0; topw[2 * t + 1] = 1.f - w0;
    atomicAdd(&counts[i0], 1);
    atomicAdd(&counts[i1], 1);
  }
}

// ---- K3: 256-aligned segment offsets, both tile tables, default slots -------
__global__ void k3_scan(const int* __restrict__ counts, int* offs, int* fill,
                        int* t128_e, int* t128_row, int* t256_e, int* t256_row,
                        int* sorted_tok, float* sorted_w) {
  if (threadIdx.x == 0) {
    int off = 0, t1 = 0, t2 = 0;
    for (int e = 0; e < NE; e++) {
      offs[e] = off; fill[e] = 0;
      int nt1 = (counts[e] + 127) >> 7;
      for (int j = 0; j < nt1; j++) { t128_e[t1] = e; t128_row[t1] = off + j * 128; t1++; }
      int nt2 = (counts[e] + 255) >> 8;
      for (int j = 0; j < nt2; j++) { t256_e[t2] = e; t256_row[t2] = off + j * 256; t2++; }
      off += nt2 * 256;
    }
    for (; t1 < MAXT; t1++)    { t128_e[t1] = -1; t128_row[t1] = 0; }
    for (; t2 < MAXT256; t2++) { t256_e[t2] = -1; t256_row[t2] = 0; }
  }
  for (int i = threadIdx.x; i < CAP; i += 256) { sorted_tok[i] = 0; sorted_w[i] = 0.f; }
}

// ---- K4: scatter token ids into expert segments -----------------------------
__global__ void k4_scatter(const int* __restrict__ topi, const float* __restrict__ topw,
                           const int* __restrict__ offs, int* __restrict__ fill,
                           int* __restrict__ sorted_tok, float* __restrict__ sorted_w) {
  int t = blockIdx.x * 256 + threadIdx.x;
#pragma unroll
  for (int k = 0; k < 2; k++) {
    int e = topi[2 * t + k];
    int p = atomicAdd(&fill[e], 1);
    int s = offs[e] + p;
    sorted_tok[s] = t;
    sorted_w[s]   = topw[2 * t + k];
  }
}

// Bank swizzle (T2): LDS rows are 64 bf16 (8 chunks of 16B); phys chunk p of
// row r holds logical chunk p ^ (r&7). Stager bakes it into the GLOBAL source
// address (global_load_lds LDS dst is linear); readers address p = c ^ (r&7).

// ---- K5: h = silu(X*W1) .* (X*W3), 256x128 dual-B, 8-wave, 4-phase/K-tile --
// Stage order per K-tile: A0, A1, B1, B3 (16KB halves, 2 gloads/thread each).
// Counted waits: vmcnt(4) at phase1 (drains cur B3 only), vmcnt(2) at phase3
// (drains next A0,A1,B1; next B3 stays in flight). Never vmcnt(0) in-loop.
#define STG2(SMN, HOFF, S0, S1, KN)                        \
  do {                                                     \
    gload16((S0) + (KN), (SMN) + (HOFF) + sd);             \
    gload16((S1) + (KN), (SMN) + (HOFF) + 4096u + sd);     \
  } while (0)

template<int CFC>
__global__ __launch_bounds__(512, 2) void k5_gemm_h8(
    const unsigned short* __restrict__ xbf,
    const unsigned short* __restrict__ w1t,   // [e][f'][d] bf16
    const unsigned short* __restrict__ w3t,
    unsigned short* __restrict__ h,           // [slot][f'] bf16
    const int* __restrict__ t256_e, const int* __restrict__ t256_row,
    const int* __restrict__ sorted_tok, int FCdyn) {
  const int FC = CFC ? CFC : FCdyn;
  extern __shared__ unsigned short sm[];      // 2 buffers x 32768 ushorts (128KiB)

  // T1: XCD-aware bijective swizzle (gridDim.x % 8 == 0 by construction)
  int nb  = gridDim.x;
  int bid = blockIdx.x;
  int nid = (bid & 7) * (nb >> 3) + (bid >> 3);
  int tile = nid % MAXT256;
  int nblk = nid / MAXT256;

  int e = t256_e[tile];
  if (e < 0) return;
  int row0 = t256_row[tile];
  int n0 = nblk * 128;
  int tid = threadIdx.x;

  // staging constants: row-within-64-group, swizzled source chunk
  int sr = tid >> 3;                          // 0..63
  int cs = ((tid & 7) ^ (sr & 7)) * 8;        // ushort offset (16B chunk)
  const unsigned short* pA0 = xbf + (size_t)sorted_tok[row0 +       sr] * HID + cs;
  const unsigned short* pA1 = xbf + (size_t)sorted_tok[row0 +  64 + sr] * HID + cs;
  const unsigned short* pA2 = xbf + (size_t)sorted_tok[row0 + 128 + sr] * HID + cs;
  const unsigned short* pA3 = xbf + (size_t)sorted_tok[row0 + 192 + sr] * HID + cs;
  size_t rb0 = ((size_t)e * FC + n0 + sr) * HID + cs;
  size_t rb1 = rb0 + (size_t)64 * HID;
  const unsigned short* pB10 = w1t + rb0;
  const unsigned short* pB11 = w1t + rb1;
  const unsigned short* pB30 = w3t + rb0;
  const unsigned short* pB31 = w3t + rb1;
  unsigned sd = (unsigned)tid * 8u;           // thread slot (ushort units)

  // fragment-read constants
  int wid = tid >> 6, lane = tid & 63, lm = lane & 15, q = lane >> 4;
  int wr = wid >> 1, wc = wid & 1;            // 4M x 2N waves
  unsigned aOff  = (unsigned)(wr * 64 + lm) * 64u;
  unsigned b1Off = 16384u + (unsigned)(wc * 64 + lm) * 64u;
  unsigned b3Off = 24576u + (unsigned)(wc * 64 + lm) * 64u;
  unsigned px0 = (unsigned)((q ^ (lm & 7)) * 8);
  unsigned px1 = (unsigned)(((4 + q) ^ (lm & 7)) * 8);

  f32x4 acc1[4][4] = {};
  f32x4 acc3[4][4] = {};
  bf16x8 af[4][2], bfr[2][2];

  // prologue: stage K-tile 0 into buf0; leave its B3 in flight
  {
    unsigned short* smn = sm;
    STG2(smn, 0u,     pA0,  pA1,  0);
    STG2(smn, 8192u,  pA2,  pA3,  0);
    STG2(smn, 16384u, pB10, pB11, 0);
    STG2(smn, 24576u, pB30, pB31, 0);
  }
  asm volatile("s_waitcnt vmcnt(2)" ::: "memory");
  __builtin_amdgcn_s_barrier();
  __builtin_amdgcn_sched_barrier(0);

#pragma unroll 1
  for (int kt = 0; kt < NKT5; kt++) {
    const unsigned short* smc = sm + ((kt & 1) ? 32768u : 0u);
    unsigned short*       smn = sm + ((kt & 1) ? 0u : 32768u);
    int kn = ((kt + 1) & (NKT5 - 1)) * 64;    // kt==15 wraps: dummy restage

    // -- phase 0: read A(all) + B1[tj01]; stage next A0; MFMA acc1 tj01 -----
#pragma unroll
    for (int ti = 0; ti < 4; ti++) {
      af[ti][0] = *(const bf16x8*)(smc + aOff + ti * 1024u + px0);
      af[ti][1] = *(const bf16x8*)(smc + aOff + ti * 1024u + px1);
    }
#pragma unroll
    for (int j = 0; j < 2; j++) {
      bfr[j][0] = *(const bf16x8*)(smc + b1Off + j * 1024u + px0);
      bfr[j][1] = *(const bf16x8*)(smc + b1Off + j * 1024u + px1);
    }
    STG2(smn, 0u, pA0, pA1, kn);
    __builtin_amdgcn_s_barrier();
    __builtin_amdgcn_sched_barrier(0);
    __builtin_amdgcn_s_setprio(1);
#pragma unroll
    for (int ti = 0; ti < 4; ti++)
#pragma unroll
      for (int j = 0; j < 2; j++) {
        acc1[ti][j] = __builtin_amdgcn_mfma_f32_16x16x32_bf16(af[ti][0], bfr[j][0], acc1[ti][j], 0, 0, 0);
        acc1[ti][j] = __builtin_amdgcn_mfma_f32_16x16x32_bf16(af[ti][1], bfr[j][1], acc1[ti][j], 0, 0, 0);
      }
    __builtin_amdgcn_s_setprio(0);

    // -- phase 1: read B1[tj23]; stage next A1; vmcnt(4); MFMA acc1 tj23 ----
#pragma unroll
    for (int j = 0; j < 2; j++) {
      bfr[j][0] = *(const bf16x8*)(smc + b1Off + 2048u + j * 1024u + px0);
      bfr[j][1] = *(const bf16x8*)(smc + b1Off + 2048u + j * 1024u + px1);
    }
    STG2(smn, 8192u, pA2, pA3, kn);
    asm volatile("s_waitcnt vmcnt(4)" ::: "memory");
    __builtin_amdgcn_s_barrier();
    __builtin_amdgcn_sched_barrier(0);
    __builtin_amdgcn_s_setprio(1);
#pragma unroll
    for (int ti = 0; ti < 4; ti++)
#pragma unroll
      for (int j = 0; j < 2; j++) {
        acc1[ti][2 + j] = __builtin_amdgcn_mfma_f32_16x16x32_bf16(af[ti][0], bfr[j][0], acc1[ti][2 + j], 0, 0, 0);
        acc1[ti][2 + j] = __builtin_amdgcn_mfma_f32_16x16x32_bf16(af[ti][1], bfr[j][1], acc1[ti][2 + j], 0, 0, 0);
      }
    __builtin_amdgcn_s_setprio(0);

    // -- phase 2: read B3[tj01]; stage next B1; MFMA acc3 tj01 --------------
#pragma unroll
    for (int j = 0; j < 2; j++) {
      bfr[j][0] = *(const bf16x8*)(smc + b3Off + j * 1024u + px0);
      bfr[j][1] = *(const bf16x8*)(smc + b3Off + j * 1024u + px1);
    }
    STG2(smn, 16384u, pB10, pB11, kn);
    __builtin_amdgcn_s_barrier();
    __builtin_amdgcn_sched_barrier(0);
    __builtin_amdgcn_s_setprio(1);
#pragma unroll
    for (int ti = 0; ti < 4; ti++)
#pragma unroll
      for (int j = 0; j < 2; j++) {
        acc3[ti][j] = __builtin_amdgcn_mfma_f32_16x16x32_bf16(af[ti][0], bfr[j][0], acc3[ti][j], 0, 0, 0);
        acc3[ti][j] = __builtin_amdgcn_mfma_f32_16x16x32_bf16(af[ti][1], bfr[j][1], acc3[ti][j], 0, 0, 0);
      }
    __builtin_amdgcn_s_setprio(0);

    // -- phase 3: read B3[tj23]; stage next B3; vmcnt(2); MFMA acc3 tj23 ----
#pragma unroll
    for (int j = 0; j < 2; j++) {
      bfr[j][0] = *(const bf16x8*)(smc + b3Off + 2048u + j * 1024u + px0);
      bfr[j][1] = *(const bf16x8*)(smc + b3Off + 2048u + j * 1024u + px1);
    }
    STG2(smn, 24576u, pB30, pB31, kn);
    asm volatile("s_waitcnt vmcnt(2)" ::: "memory");
    __builtin_amdgcn_s_barrier();
    __builtin_amdgcn_sched_barrier(0);
    __builtin_amdgcn_s_setprio(1);
#pragma unroll
    for (int ti = 0; ti < 4; ti++)
#pragma unroll
      for (int j = 0; j < 2; j++) {
        acc3[ti][2 + j] = __builtin_amdgcn_mfma_f32_16x16x32_bf16(af[ti][0], bfr[j][0], acc3[ti][2 + j], 0, 0, 0);
        acc3[ti][2 + j] = __builtin_amdgcn_mfma_f32_16x16x32_bf16(af[ti][1], bfr[j][1], acc3[ti][2 + j], 0, 0, 0);
      }
    __builtin_amdgcn_s_setprio(0);
  }
  asm volatile("s_waitcnt vmcnt(0)" ::: "memory");

  // epilogue: silu(h1)*h3 -> bf16 h
#pragma unroll
  for (int ti = 0; ti < 4; ti++)
#pragma unroll
    for (int tj = 0; tj < 4; tj++)
#pragma unroll
      for (int r = 0; r < 4; r++) {
        float v1 = acc1[ti][tj][r];
        float v3 = acc3[ti][tj][r];
        float hv = (v1 / (1.f + __expf(-v1))) * v3;
        int grow = row0 + wr * 64 + ti * 16 + q * 4 + r;
        int gcol = n0 + wc * 64 + tj * 16 + lm;
        h[(size_t)grow * FC + gcol] = f2bf(hv);
      }
}

// ---- K6: out += w * (H_chunk * W2t_chunk), 128x128 tile, atomic scatter -----
template<int CFC>
__global__ __launch_bounds__(256) void k6_gemm_out(
    const unsigned short* __restrict__ h,     // [slot][f'] bf16
    const unsigned short* __restrict__ w2t,   // [e][d][f'] bf16
    float* __restrict__ out,
    const int* __restrict__ tile_e, const int* __restrict__ tile_row,
    const int* __restrict__ sorted_tok, const float* __restrict__ sorted_w,
    int FCdyn) {
  const int FC = CFC ? CFC : FCdyn;
  __shared__ unsigned short lsA[128 * 32];
  __shared__ unsigned short lsB[128 * 32];
  __shared__ int   toks[128];
  __shared__ float wts[128];

  // T1: XCD swizzle — each XCD owns one n0-panel x all tiles (576 = 8*72)
  int nbk  = (int)(gridDim.x * gridDim.y);
  int bidl = (int)(blockIdx.x + gridDim.x * blockIdx.y);
  int nidk = (bidl & 7) * (nbk >> 3) + (bidl >> 3);
  int tile = nidk % (int)gridDim.x;
  int yb   = nidk / (int)gridDim.x;

  int e = tile_e[tile];
  if (e < 0) return;
  int row0 = tile_row[tile];
  int n0 = yb * 128;
  int tid = threadIdx.x;

  if (tid < 128) { toks[tid] = sorted_tok[row0 + tid]; wts[tid] = sorted_w[row0 + tid]; }

  int kc = tid & 3, lr = tid >> 2;
  int g = (kc ^ ((lr >> 1) & 3)) * 8;
  const unsigned short* ga0 = h + (size_t)(row0 + lr) * FC + g;
  const unsigned short* ga1 = h + (size_t)(row0 + lr + 64) * FC + g;
  const unsigned short* gb0 = w2t + ((size_t)e * HID + n0 + lr) * FC + g;
  const unsigned short* gb1 = w2t + ((size_t)e * HID + n0 + lr + 64) * FC + g;
  unsigned short* la0 = lsA + tid * 8;
  unsigned short* la1 = lsA + (256 + tid) * 8;
  unsigned short* lb0 = lsB + tid * 8;
  unsigned short* lb1 = lsB + (256 + tid) * 8;

  int wid = tid >> 6, lane = tid & 63, lm = lane & 15, q = lane >> 4;
  int wr = wid >> 1, wc = wid & 1;
  int qs = (q ^ ((lm >> 1) & 3)) * 8;
  const unsigned short* As = lsA + (wr * 64 + lm) * 32 + qs;
  const unsigned short* Bs = lsB + (wc * 64 + lm) * 32 + qs;

  f32x4 acc[4][4] = {};

#pragma unroll 1
  for (int ks = 0; ks < FC / 32; ks++) {
    __syncthreads();
    int k0 = ks * 32;
    gload16(ga0 + k0, la0);
    gload16(ga1 + k0, la1);
    gload16(gb0 + k0, lb0);
    gload16(gb1 + k0, lb1);
    __syncthreads();
    bf16x8 a[4], b[4];
#pragma unroll
    for (int ti = 0; ti < 4; ti++) a[ti] = *(const bf16x8*)(As + ti * 512);
#pragma unroll
    for (int tj = 0; tj < 4; tj++) b[tj] = *(const bf16x8*)(Bs + tj * 512);
#pragma unroll
    for (int ti = 0; ti < 4; ti++)
#pragma unroll
      for (int tj = 0; tj < 4; tj++)
        acc[ti][tj] = __builtin_amdgcn_mfma_f32_16x16x32_bf16(a[ti], b[tj], acc[ti][tj], 0, 0, 0);
  }

#pragma unroll
  for (int ti = 0; ti < 4; ti++)
#pragma unroll
    for (int r = 0; r < 4; r++) {
      int lrow = wr * 64 + ti * 16 + q * 4 + r;
      float wt = wts[lrow];
      if (wt != 0.f) {
        int trow = toks[lrow];
#pragma unroll
        for (int tj = 0; tj < 4; tj++) {
          int gcol = n0 + wc * 64 + tj * 16 + lm;
          atomicAdd(&out[(size_t)trow * HID + gcol], acc[ti][tj][r] * wt);
        }
      }
    }
}

// ---------------------------------------------------------------------------
extern "C" void kernel_launch(void* const* d_in, const int* in_sizes, int n_in,
                              void* d_out, int out_size, void* d_ws, size_t ws_size,
                              hipStream_t stream) {
  const float* x  = (const float*)d_in[0];
  const float* gw = (const float*)d_in[1];
  const float* gb = (const float*)d_in[2];
  const float* w1 = (const float*)d_in[3];
  const float* w3 = (const float*)d_in[4];
  const float* w2 = (const float*)d_in[5];
  float* out = (float*)d_out;

  char* ws = (char*)d_ws;
  int*   counts     = (int*)(ws + 0);        // 8
  int*   fill       = (int*)(ws + 32);       // 8
  int*   offs       = (int*)(ws + 64);       // 8
  int*   t128_e     = (int*)(ws + 96);       // 80
  int*   t128_row   = (int*)(ws + 416);      // 80
  int*   t256_e     = (int*)(ws + 736);      // 40
  int*   t256_row   = (int*)(ws + 896);      // 40  (ends 1056)
  int*   topi       = (int*)(ws + 2048);     // 8192 ints  -> 34816
  float* topw       = (float*)(ws + 34816);  // 8192 f     -> 67584
  int*   sorted_tok = (int*)(ws + 67584);    // CAP ints   -> 108544
  float* sorted_w   = (float*)(ws + 108544); // CAP f      -> 149504
  unsigned short* xbf = (unsigned short*)(ws + 149504); // 8MB -> 8538112
  const size_t base = 8538112ull;

  int FC = FFN;
  while (FC > 128) {
    size_t W  = (size_t)NE * FC * HID * 2;
    size_t Hb = (size_t)CAP * FC * 2;
    if (base + 3 * W + Hb <= ws_size) break;
    FC >>= 1;
  }
  size_t W = (size_t)NE * FC * HID * 2;
  unsigned short* w1t  = (unsigned short*)(ws + base);
  unsigned short* w3t  = (unsigned short*)(ws + base + W);
  unsigned short* w2t  = (unsigned short*)(ws + base + 2 * W);
  unsigned short* hbuf = (unsigned short*)(ws + base + 3 * W);
  int nc = FFN / FC;

  static bool attr_set = false;
  if (!attr_set) {
    hipFuncSetAttribute((const void*)k5_gemm_h8<4096>, hipFuncAttributeMaxDynamicSharedMemorySize, 131072);
    hipFuncSetAttribute((const void*)k5_gemm_h8<2048>, hipFuncAttributeMaxDynamicSharedMemorySize, 131072);
    hipFuncSetAttribute((const void*)k5_gemm_h8<1024>, hipFuncAttributeMaxDynamicSharedMemorySize, 131072);
    hipFuncSetAttribute((const void*)k5_gemm_h8<0>,    hipFuncAttributeMaxDynamicSharedMemorySize, 131072);
    attr_set = true;
  }

  k0_zero_cvt<<<4096, 256, 0, stream>>>(x, xbf, out, counts);
  k2_router<<<1024, 256, 0, stream>>>(x, gw, gb, topi, topw, counts);
  k3_scan<<<1, 256, 0, stream>>>(counts, offs, fill, t128_e, t128_row,
                                 t256_e, t256_row, sorted_tok, sorted_w);
  k4_scatter<<<16, 256, 0, stream>>>(topi, topw, offs, fill, sorted_tok, sorted_w);

  for (int c = 0; c < nc; c++) {
    int c0 = c * FC;
    // w1/w3 [e][HID][FFN] cols chunk -> [e][FC][HID] (fused, grid.z=16)
    k1_transpose<<<dim3(FC / 64, HID / 64, 16), 256, 0, stream>>>(
        w1, w1t, w3, w3t, HID, FFN, 0, c0, HID, FC);
    // w2 [e][FFN][HID] rows chunk -> [e][HID][FC]
    k1_transpose<<<dim3(HID / 64, FC / 64, 8), 256, 0, stream>>>(
        w2, w2t, nullptr, nullptr, FFN, HID, c0, 0, FC, HID);
    dim3 g5(MAXT256 * (FC / 128));
    if (FC == 4096) {
      k5_gemm_h8<4096><<<g5, 512, 131072, stream>>>(
          xbf, w1t, w3t, hbuf, t256_e, t256_row, sorted_tok, FC);
      k6_gemm_out<4096><<<dim3(MAXT, HID / 128), 256, 0, stream>>>(
          hbuf, w2t, out, t128_e, t128_row, sorted_tok, sorted_w, FC);
    } else if (FC == 2048) {
      k5_gemm_h8<2048><<<g5, 512, 131072, stream>>>(
          xbf, w1t, w3t, hbuf, t256_e, t256_row, sorted_tok, FC);
      k6_gemm_out<2048><<<dim3(MAXT, HID / 128), 256, 0, stream>>>(
          hbuf, w2t, out, t128_e, t128_row, sorted_tok, sorted_w, FC);
    } else if (FC == 1024) {
      k5_gemm_h8<1024><<<g5, 512, 131072, stream>>>(
          xbf, w1t, w3t, hbuf, t256_e, t256_row, sorted_tok, FC);
      k6_gemm_out<1024><<<dim3(MAXT, HID / 128), 256, 0, stream>>>(
          hbuf, w2t, out, t128_e, t128_row, sorted_tok, sorted_w, FC);
    } else {
      k5_gemm_h8<0><<<g5, 512, 131072, stream>>>(
          xbf, w1t, w3t, hbuf, t256_e, t256_row, sorted_tok, FC);
      k6_gemm_out<0><<<dim3(MAXT, HID / 128), 256, 0, stream>>>(
          hbuf, w2t, out, t128_e, t128_row, sorted_tok, sorted_w, FC);
    }
  }
}

// Round 2
// 838.386 us; speedup vs baseline: 1.1169x; 1.0391x over previous
//
#include <hip/hip_runtime.h>

// ---------------------------------------------------------------------------
// BlockSparseMoE: T=4096 tokens, HID=1024, FFN=4096, E=8, top-2, fp32 in/out.
// route (fp32) -> permute tokens into 256-aligned expert segments -> bf16 MFMA
// grouped GEMMs with global_load_lds(16B) staging.
// R5: k6 ported to k5's proven 4-phase/counted-vmcnt schedule (T3+T4+T5),
// 256x256 tile, dual-B = (w2t rows n0..127, n0+128..255), grid 160 (one
// occupancy pass), weighted atomic-scatter epilogue. k5 untouched from R4.
// ---------------------------------------------------------------------------

#define NTOK 4096
#define HID  1024
#define FFN  4096
#define NE   8
#define CAP  10240    // 256-aligned slots: 8192 + 8*255 = 10232 <= 10240
#define MAXT 72       // 128-row tiles (legacy table, still emitted)
#define MAXT256 40    // 256-row tiles: sum ceil(c/256) <= 39
#define NKT5 16       // HID/64 K-tiles in k5

typedef __bf16 bf16x8 __attribute__((ext_vector_type(8)));
typedef float  f32x4  __attribute__((ext_vector_type(4)));

typedef __attribute__((address_space(3))) unsigned int       lds_uint;
typedef const __attribute__((address_space(1))) unsigned int glob_uint;

__device__ __forceinline__ unsigned short f2bf(float f) {
  union { float f; unsigned u; } v; v.f = f;
  return (unsigned short)((v.u + 0x7FFFu + ((v.u >> 16) & 1u)) >> 16); // RNE
}

__device__ __forceinline__ void gload16(const void* g, void* l) {
  __builtin_amdgcn_global_load_lds((glob_uint*)g, (lds_uint*)l, 16, 0, 0);
}

// ---- K0: zero out, convert x -> bf16, zero expert counts --------------------
__global__ void k0_zero_cvt(const float* __restrict__ x,
                            unsigned short* __restrict__ xbf,
                            float* __restrict__ out,
                            int* __restrict__ counts) {
  int i = blockIdx.x * 256 + threadIdx.x;
  const float4* x4 = (const float4*)x;
  float4 v = x4[i];
  uint2 p;
  p.x = (unsigned)f2bf(v.x) | ((unsigned)f2bf(v.y) << 16);
  p.y = (unsigned)f2bf(v.z) | ((unsigned)f2bf(v.w) << 16);
  ((uint2*)xbf)[i] = p;
  ((float4*)out)[i] = make_float4(0.f, 0.f, 0.f, 0.f);
  if (i < NE) counts[i] = 0;
}

// ---- K1: vectorized 64x64 transpose + fp32->bf16 ----------------------------
__global__ __launch_bounds__(256) void k1_transpose(
    const float* __restrict__ s0, unsigned short* __restrict__ d0,
    const float* __restrict__ s1, unsigned short* __restrict__ d1,
    int Rfull, int Cfull, int rg0, int cg0, int RW, int CW) {
  __shared__ unsigned short tile[64 * 72];   // pitch 72 (144B): breaks read conflicts
  int z = blockIdx.z;
  const float* src = (z < 8 ? s0 : s1) + (size_t)(z & 7) * Rfull * Cfull;
  unsigned short* dst = (z < 8 ? d0 : d1) + (size_t)(z & 7) * RW * CW;
  int c0 = blockIdx.x * 64;   // local col tile
  int r0 = blockIdx.y * 64;   // local row tile
  int t = threadIdx.x;
  int q = t >> 4, p = t & 15;

  const float4* s4 = (const float4*)(src + (size_t)(rg0 + r0 + 4 * q) * Cfull
                                     + cg0 + c0) + p;
  unsigned short v[4][4];
#pragma unroll
  for (int u = 0; u < 4; u++) {
    float4 xv = s4[(size_t)u * (Cfull >> 2)];
    v[u][0] = f2bf(xv.x); v[u][1] = f2bf(xv.y);
    v[u][2] = f2bf(xv.z); v[u][3] = f2bf(xv.w);
  }
#pragma unroll
  for (int j = 0; j < 4; j++) {
    ushort4 w = make_ushort4(v[0][j], v[1][j], v[2][j], v[3][j]);
    *(ushort4*)&tile[(4 * p + j) * 72 + 4 * q] = w;
  }
  __syncthreads();
  int b = t & 7;
#pragma unroll
  for (int vi = 0; vi < 2; vi++) {
    int c = (t >> 3) + 32 * vi;                       // 0..63
    uint4 w = *(const uint4*)&tile[c * 72 + 8 * b];
    *(uint4*)(dst + (size_t)(c0 + c) * RW + r0 + 8 * b) = w;
  }
}

// ---- K2: router, one wave per token ----------------------------------------
__global__ void k2_router(const float* __restrict__ x,
                          const float* __restrict__ gw,
                          const float* __restrict__ gb,
                          int* __restrict__ topi, float* __restrict__ topw,
                          int* __restrict__ counts) {
  int wid = threadIdx.x >> 6, lane = threadIdx.x & 63;
  int t = blockIdx.x * 4 + wid;
  const float4* x4 = (const float4*)(x + (size_t)t * HID);
  const float4* g4 = (const float4*)gw;
  float acc[8];
#pragma unroll
  for (int e = 0; e < 8; e++) acc[e] = 0.f;
#pragma unroll
  for (int i = 0; i < 4; i++) {
    float4 xv = x4[i * 64 + lane];
    int dbase = (i * 64 + lane) * 4;
    float xs[4] = {xv.x, xv.y, xv.z, xv.w};
#pragma unroll
    for (int j = 0; j < 4; j++) {
      float4 ga  = g4[(dbase + j) * 2];
      float4 gbv = g4[(dbase + j) * 2 + 1];
      acc[0] += xs[j] * ga.x;  acc[1] += xs[j] * ga.y;
      acc[2] += xs[j] * ga.z;  acc[3] += xs[j] * ga.w;
      acc[4] += xs[j] * gbv.x; acc[5] += xs[j] * gbv.y;
      acc[6] += xs[j] * gbv.z; acc[7] += xs[j] * gbv.w;
    }
  }
#pragma unroll
  for (int e = 0; e < 8; e++)
#pragma unroll
    for (int m = 1; m < 64; m <<= 1) acc[e] += __shfl_xor(acc[e], m);
  if (lane == 0) {
    float lg[8];
#pragma unroll
    for (int e = 0; e < 8; e++) lg[e] = acc[e] + gb[e];
    int i0 = 0; float m0 = lg[0];
#pragma unroll
    for (int e = 1; e < 8; e++) if (lg[e] > m0) { m0 = lg[e]; i0 = e; }
    int i1 = -1; float m1 = -1e30f;
#pragma unroll
    for (int e = 0; e < 8; e++) if (e != i0 && lg[e] > m1) { m1 = lg[e]; i1 = e; }
    float w0 = 1.f / (1.f + __expf(m1 - m0));   // == p0/(p0+p1) renormalized
    topi[2 * t] = i0; topi[2 * t + 1] = i1;
    topw[2 * t] = w0; topw[2 * t + 1] = 1.f - w0;
    atomicAdd(&counts[i0], 1);
    atomicAdd(&counts[i1], 1);
  }
}

// ---- K3: 256-aligned segment offsets, both tile tables, default slots -------
__global__ void k3_scan(const int* __restrict__ counts, int* offs, int* fill,
                        int* t128_e, int* t128_row, int* t256_e, int* t256_row,
                        int* sorted_tok, float* sorted_w) {
  if (threadIdx.x == 0) {
    int off = 0, t1 = 0, t2 = 0;
    for (int e = 0; e < NE; e++) {
      offs[e] = off; fill[e] = 0;
      int nt1 = (counts[e] + 127) >> 7;
      for (int j = 0; j < nt1; j++) { t128_e[t1] = e; t128_row[t1] = off + j * 128; t1++; }
      int nt2 = (counts[e] + 255) >> 8;
      for (int j = 0; j < nt2; j++) { t256_e[t2] = e; t256_row[t2] = off + j * 256; t2++; }
      off += nt2 * 256;
    }
    for (; t1 < MAXT; t1++)    { t128_e[t1] = -1; t128_row[t1] = 0; }
    for (; t2 < MAXT256; t2++) { t256_e[t2] = -1; t256_row[t2] = 0; }
  }
  for (int i = threadIdx.x; i < CAP; i += 256) { sorted_tok[i] = 0; sorted_w[i] = 0.f; }
}

// ---- K4: scatter token ids into expert segments -----------------------------
__global__ void k4_scatter(const int* __restrict__ topi, const float* __restrict__ topw,
                           const int* __restrict__ offs, int* __restrict__ fill,
                           int* __restrict__ sorted_tok, float* __restrict__ sorted_w) {
  int t = blockIdx.x * 256 + threadIdx.x;
#pragma unroll
  for (int k = 0; k < 2; k++) {
    int e = topi[2 * t + k];
    int p = atomicAdd(&fill[e], 1);
    int s = offs[e] + p;
    sorted_tok[s] = t;
    sorted_w[s]   = topw[2 * t + k];
  }
}

// Bank swizzle (T2): LDS rows are 64 bf16 (8 chunks of 16B); phys chunk p of
// row r holds logical chunk p ^ (r&7). Stager bakes it into the GLOBAL source
// address (global_load_lds LDS dst is linear); readers address p = c ^ (r&7).

#define STG2(SMN, HOFF, S0, S1, KN)                        \
  do {                                                     \
    gload16((S0) + (KN), (SMN) + (HOFF) + sd);             \
    gload16((S1) + (KN), (SMN) + (HOFF) + 4096u + sd);     \
  } while (0)

// ---- K5: h = silu(X*W1) .* (X*W3), 256x128 dual-B, 8-wave, 4-phase/K-tile --
// Stage order per K-tile: A0, A1, B1, B3 (16KB halves, 2 gloads/thread each).
// Counted waits: vmcnt(4) at phase1 (drains cur B3 only), vmcnt(2) at phase3
// (drains next A0,A1,B1; next B3 stays in flight). Never vmcnt(0) in-loop.
template<int CFC>
__global__ __launch_bounds__(512, 2) void k5_gemm_h8(
    const unsigned short* __restrict__ xbf,
    const unsigned short* __restrict__ w1t,   // [e][f'][d] bf16
    const unsigned short* __restrict__ w3t,
    unsigned short* __restrict__ h,           // [slot][f'] bf16
    const int* __restrict__ t256_e, const int* __restrict__ t256_row,
    const int* __restrict__ sorted_tok, int FCdyn) {
  const int FC = CFC ? CFC : FCdyn;
  extern __shared__ unsigned short sm[];      // 2 buffers x 32768 ushorts (128KiB)

  // T1: XCD-aware bijective swizzle (gridDim.x % 8 == 0 by construction)
  int nb  = gridDim.x;
  int bid = blockIdx.x;
  int nid = (bid & 7) * (nb >> 3) + (bid >> 3);
  int tile = nid % MAXT256;
  int nblk = nid / MAXT256;

  int e = t256_e[tile];
  if (e < 0) return;
  int row0 = t256_row[tile];
  int n0 = nblk * 128;
  int tid = threadIdx.x;

  // staging constants: row-within-64-group, swizzled source chunk
  int sr = tid >> 3;                          // 0..63
  int cs = ((tid & 7) ^ (sr & 7)) * 8;        // ushort offset (16B chunk)
  const unsigned short* pA0 = xbf + (size_t)sorted_tok[row0 +       sr] * HID + cs;
  const unsigned short* pA1 = xbf + (size_t)sorted_tok[row0 +  64 + sr] * HID + cs;
  const unsigned short* pA2 = xbf + (size_t)sorted_tok[row0 + 128 + sr] * HID + cs;
  const unsigned short* pA3 = xbf + (size_t)sorted_tok[row0 + 192 + sr] * HID + cs;
  size_t rb0 = ((size_t)e * FC + n0 + sr) * HID + cs;
  size_t rb1 = rb0 + (size_t)64 * HID;
  const unsigned short* pB10 = w1t + rb0;
  const unsigned short* pB11 = w1t + rb1;
  const unsigned short* pB30 = w3t + rb0;
  const unsigned short* pB31 = w3t + rb1;
  unsigned sd = (unsigned)tid * 8u;           // thread slot (ushort units)

  // fragment-read constants
  int wid = tid >> 6, lane = tid & 63, lm = lane & 15, q = lane >> 4;
  int wr = wid >> 1, wc = wid & 1;            // 4M x 2N waves
  unsigned aOff  = (unsigned)(wr * 64 + lm) * 64u;
  unsigned b1Off = 16384u + (unsigned)(wc * 64 + lm) * 64u;
  unsigned b3Off = 24576u + (unsigned)(wc * 64 + lm) * 64u;
  unsigned px0 = (unsigned)((q ^ (lm & 7)) * 8);
  unsigned px1 = (unsigned)(((4 + q) ^ (lm & 7)) * 8);

  f32x4 acc1[4][4] = {};
  f32x4 acc3[4][4] = {};
  bf16x8 af[4][2], bfr[2][2];

  // prologue: stage K-tile 0 into buf0; leave its B3 in flight
  {
    unsigned short* smn = sm;
    STG2(smn, 0u,     pA0,  pA1,  0);
    STG2(smn, 8192u,  pA2,  pA3,  0);
    STG2(smn, 16384u, pB10, pB11, 0);
    STG2(smn, 24576u, pB30, pB31, 0);
  }
  asm volatile("s_waitcnt vmcnt(2)" ::: "memory");
  __builtin_amdgcn_s_barrier();
  __builtin_amdgcn_sched_barrier(0);

#pragma unroll 1
  for (int kt = 0; kt < NKT5; kt++) {
    const unsigned short* smc = sm + ((kt & 1) ? 32768u : 0u);
    unsigned short*       smn = sm + ((kt & 1) ? 0u : 32768u);
    int kn = ((kt + 1) & (NKT5 - 1)) * 64;    // kt==15 wraps: dummy restage

    // -- phase 0: read A(all) + B1[tj01]; stage next A0; MFMA acc1 tj01 -----
#pragma unroll
    for (int ti = 0; ti < 4; ti++) {
      af[ti][0] = *(const bf16x8*)(smc + aOff + ti * 1024u + px0);
      af[ti][1] = *(const bf16x8*)(smc + aOff + ti * 1024u + px1);
    }
#pragma unroll
    for (int j = 0; j < 2; j++) {
      bfr[j][0] = *(const bf16x8*)(smc + b1Off + j * 1024u + px0);
      bfr[j][1] = *(const bf16x8*)(smc + b1Off + j * 1024u + px1);
    }
    STG2(smn, 0u, pA0, pA1, kn);
    __builtin_amdgcn_s_barrier();
    __builtin_amdgcn_sched_barrier(0);
    __builtin_amdgcn_s_setprio(1);
#pragma unroll
    for (int ti = 0; ti < 4; ti++)
#pragma unroll
      for (int j = 0; j < 2; j++) {
        acc1[ti][j] = __builtin_amdgcn_mfma_f32_16x16x32_bf16(af[ti][0], bfr[j][0], acc1[ti][j], 0, 0, 0);
        acc1[ti][j] = __builtin_amdgcn_mfma_f32_16x16x32_bf16(af[ti][1], bfr[j][1], acc1[ti][j], 0, 0, 0);
      }
    __builtin_amdgcn_s_setprio(0);

    // -- phase 1: read B1[tj23]; stage next A1; vmcnt(4); MFMA acc1 tj23 ----
#pragma unroll
    for (int j = 0; j < 2; j++) {
      bfr[j][0] = *(const bf16x8*)(smc + b1Off + 2048u + j * 1024u + px0);
      bfr[j][1] = *(const bf16x8*)(smc + b1Off + 2048u + j * 1024u + px1);
    }
    STG2(smn, 8192u, pA2, pA3, kn);
    asm volatile("s_waitcnt vmcnt(4)" ::: "memory");
    __builtin_amdgcn_s_barrier();
    __builtin_amdgcn_sched_barrier(0);
    __builtin_amdgcn_s_setprio(1);
#pragma unroll
    for (int ti = 0; ti < 4; ti++)
#pragma unroll
      for (int j = 0; j < 2; j++) {
        acc1[ti][2 + j] = __builtin_amdgcn_mfma_f32_16x16x32_bf16(af[ti][0], bfr[j][0], acc1[ti][2 + j], 0, 0, 0);
        acc1[ti][2 + j] = __builtin_amdgcn_mfma_f32_16x16x32_bf16(af[ti][1], bfr[j][1], acc1[ti][2 + j], 0, 0, 0);
      }
    __builtin_amdgcn_s_setprio(0);

    // -- phase 2: read B3[tj01]; stage next B1; MFMA acc3 tj01 --------------
#pragma unroll
    for (int j = 0; j < 2; j++) {
      bfr[j][0] = *(const bf16x8*)(smc + b3Off + j * 1024u + px0);
      bfr[j][1] = *(const bf16x8*)(smc + b3Off + j * 1024u + px1);
    }
    STG2(smn, 16384u, pB10, pB11, kn);
    __builtin_amdgcn_s_barrier();
    __builtin_amdgcn_sched_barrier(0);
    __builtin_amdgcn_s_setprio(1);
#pragma unroll
    for (int ti = 0; ti < 4; ti++)
#pragma unroll
      for (int j = 0; j < 2; j++) {
        acc3[ti][j] = __builtin_amdgcn_mfma_f32_16x16x32_bf16(af[ti][0], bfr[j][0], acc3[ti][j], 0, 0, 0);
        acc3[ti][j] = __builtin_amdgcn_mfma_f32_16x16x32_bf16(af[ti][1], bfr[j][1], acc3[ti][j], 0, 0, 0);
      }
    __builtin_amdgcn_s_setprio(0);

    // -- phase 3: read B3[tj23]; stage next B3; vmcnt(2); MFMA acc3 tj23 ----
#pragma unroll
    for (int j = 0; j < 2; j++) {
      bfr[j][0] = *(const bf16x8*)(smc + b3Off + 2048u + j * 1024u + px0);
      bfr[j][1] = *(const bf16x8*)(smc + b3Off + 2048u + j * 1024u + px1);
    }
    STG2(smn, 24576u, pB30, pB31, kn);
    asm volatile("s_waitcnt vmcnt(2)" ::: "memory");
    __builtin_amdgcn_s_barrier();
    __builtin_amdgcn_sched_barrier(0);
    __builtin_amdgcn_s_setprio(1);
#pragma unroll
    for (int ti = 0; ti < 4; ti++)
#pragma unroll
      for (int j = 0; j < 2; j++) {
        acc3[ti][2 + j] = __builtin_amdgcn_mfma_f32_16x16x32_bf16(af[ti][0], bfr[j][0], acc3[ti][2 + j], 0, 0, 0);
        acc3[ti][2 + j] = __builtin_amdgcn_mfma_f32_16x16x32_bf16(af[ti][1], bfr[j][1], acc3[ti][2 + j], 0, 0, 0);
      }
    __builtin_amdgcn_s_setprio(0);
  }
  asm volatile("s_waitcnt vmcnt(0)" ::: "memory");

  // epilogue: silu(h1)*h3 -> bf16 h
#pragma unroll
  for (int ti = 0; ti < 4; ti++)
#pragma unroll
    for (int tj = 0; tj < 4; tj++)
#pragma unroll
      for (int r = 0; r < 4; r++) {
        float v1 = acc1[ti][tj][r];
        float v3 = acc3[ti][tj][r];
        float hv = (v1 / (1.f + __expf(-v1))) * v3;
        int grow = row0 + wr * 64 + ti * 16 + q * 4 + r;
        int gcol = n0 + wc * 64 + tj * 16 + lm;
        h[(size_t)grow * FC + gcol] = f2bf(hv);
      }
}

// ---- K6: out += w * (H * W2t), 256x256 dual-B, 8-wave, 4-phase/K-tile ------
// Identical schedule to k5: B1 = w2t rows [n0, n0+128), B3 = [n0+128, n0+256).
// Epilogue: weighted atomic scatter of acc1 (cols n0..+127) and acc3 (+128).
template<int CFC>
__global__ __launch_bounds__(512, 2) void k6_gemm_o8(
    const unsigned short* __restrict__ h,     // [slot][f'] bf16
    const unsigned short* __restrict__ w2t,   // [e][d][f'] bf16
    float* __restrict__ out,
    const int* __restrict__ t256_e, const int* __restrict__ t256_row,
    const int* __restrict__ sorted_tok, const float* __restrict__ sorted_w,
    int FCdyn) {
  const int FC = CFC ? CFC : FCdyn;
  const int NKT = FC / 64;
  extern __shared__ unsigned short sm[];      // 2 buffers x 32768 ushorts (128KiB)
  __shared__ int   toks[256];
  __shared__ float wts[256];

  // T1: XCD swizzle; grid = MAXT256*4 = 160 (divisible by 8). Consecutive nid
  // within an XCD walk tiles at fixed nblk -> same-expert B panels L2-local.
  int nb  = gridDim.x;
  int bid = blockIdx.x;
  int nid = (bid & 7) * (nb >> 3) + (bid >> 3);
  int tile = nid % MAXT256;
  int nblk = nid / MAXT256;

  int e = t256_e[tile];
  if (e < 0) return;
  int row0 = t256_row[tile];
  int n0 = nblk * 256;
  int tid = threadIdx.x;

  if (tid < 256) { toks[tid] = sorted_tok[row0 + tid]; wts[tid] = sorted_w[row0 + tid]; }

  // staging constants
  int sr = tid >> 3;                          // 0..63
  int cs = ((tid & 7) ^ (sr & 7)) * 8;        // swizzled 16B chunk (ushorts)
  const unsigned short* pA0 = h + (size_t)(row0 +       sr) * FC + cs;
  const unsigned short* pA1 = h + (size_t)(row0 +  64 + sr) * FC + cs;
  const unsigned short* pA2 = h + (size_t)(row0 + 128 + sr) * FC + cs;
  const unsigned short* pA3 = h + (size_t)(row0 + 192 + sr) * FC + cs;
  size_t rb = ((size_t)e * HID + n0 + sr) * FC + cs;
  const unsigned short* pB10 = w2t + rb;                       // d = n0+sr
  const unsigned short* pB11 = w2t + rb + (size_t)64  * FC;    // d = n0+64+sr
  const unsigned short* pB30 = w2t + rb + (size_t)128 * FC;    // d = n0+128+sr
  const unsigned short* pB31 = w2t + rb + (size_t)192 * FC;    // d = n0+192+sr
  unsigned sd = (unsigned)tid * 8u;

  // fragment-read constants
  int wid = tid >> 6, lane = tid & 63, lm = lane & 15, q = lane >> 4;
  int wr = wid >> 1, wc = wid & 1;            // 4M x 2N waves
  unsigned aOff  = (unsigned)(wr * 64 + lm) * 64u;
  unsigned b1Off = 16384u + (unsigned)(wc * 64 + lm) * 64u;
  unsigned b3Off = 24576u + (unsigned)(wc * 64 + lm) * 64u;
  unsigned px0 = (unsigned)((q ^ (lm & 7)) * 8);
  unsigned px1 = (unsigned)(((4 + q) ^ (lm & 7)) * 8);

  f32x4 acc1[4][4] = {};
  f32x4 acc3[4][4] = {};
  bf16x8 af[4][2], bfr[2][2];

  // prologue: stage K-tile 0 into buf0; leave its B3 in flight
  {
    unsigned short* smn = sm;
    STG2(smn, 0u,     pA0,  pA1,  0);
    STG2(smn, 8192u,  pA2,  pA3,  0);
    STG2(smn, 16384u, pB10, pB11, 0);
    STG2(smn, 24576u, pB30, pB31, 0);
  }
  asm volatile("s_waitcnt vmcnt(2)" ::: "memory");
  __builtin_amdgcn_s_barrier();
  __builtin_amdgcn_sched_barrier(0);

#pragma unroll 1
  for (int kt = 0; kt < NKT; kt++) {
    const unsigned short* smc = sm + ((kt & 1) ? 32768u : 0u);
    unsigned short*       smn = sm + ((kt & 1) ? 0u : 32768u);
    int kn = (kt + 1 == NKT ? 0 : kt + 1) * 64;   // last iter: dummy restage

    // -- phase 0: read A(all) + B1[tj01]; stage next A0; MFMA acc1 tj01 -----
#pragma unroll
    for (int ti = 0; ti < 4; ti++) {
      af[ti][0] = *(const bf16x8*)(smc + aOff + ti * 1024u + px0);
      af[ti][1] = *(const bf16x8*)(smc + aOff + ti * 1024u + px1);
    }
#pragma unroll
    for (int j = 0; j < 2; j++) {
      bfr[j][0] = *(const bf16x8*)(smc + b1Off + j * 1024u + px0);
      bfr[j][1] = *(const bf16x8*)(smc + b1Off + j * 1024u + px1);
    }
    STG2(smn, 0u, pA0, pA1, kn);
    __builtin_amdgcn_s_barrier();
    __builtin_amdgcn_sched_barrier(0);
    __builtin_amdgcn_s_setprio(1);
#pragma unroll
    for (int ti = 0; ti < 4; ti++)
#pragma unroll
      for (int j = 0; j < 2; j++) {
        acc1[ti][j] = __builtin_amdgcn_mfma_f32_16x16x32_bf16(af[ti][0], bfr[j][0], acc1[ti][j], 0, 0, 0);
        acc1[ti][j] = __builtin_amdgcn_mfma_f32_16x16x32_bf16(af[ti][1], bfr[j][1], acc1[ti][j], 0, 0, 0);
      }
    __builtin_amdgcn_s_setprio(0);

    // -- phase 1: read B1[tj23]; stage next A1; vmcnt(4); MFMA acc1 tj23 ----
#pragma unroll
    for (int j = 0; j < 2; j++) {
      bfr[j][0] = *(const bf16x8*)(smc + b1Off + 2048u + j * 1024u + px0);
      bfr[j][1] = *(const bf16x8*)(smc + b1Off + 2048u + j * 1024u + px1);
    }
    STG2(smn, 8192u, pA2, pA3, kn);
    asm volatile("s_waitcnt vmcnt(4)" ::: "memory");
    __builtin_amdgcn_s_barrier();
    __builtin_amdgcn_sched_barrier(0);
    __builtin_amdgcn_s_setprio(1);
#pragma unroll
    for (int ti = 0; ti < 4; ti++)
#pragma unroll
      for (int j = 0; j < 2; j++) {
        acc1[ti][2 + j] = __builtin_amdgcn_mfma_f32_16x16x32_bf16(af[ti][0], bfr[j][0], acc1[ti][2 + j], 0, 0, 0);
        acc1[ti][2 + j] = __builtin_amdgcn_mfma_f32_16x16x32_bf16(af[ti][1], bfr[j][1], acc1[ti][2 + j], 0, 0, 0);
      }
    __builtin_amdgcn_s_setprio(0);

    // -- phase 2: read B3[tj01]; stage next B1; MFMA acc3 tj01 --------------
#pragma unroll
    for (int j = 0; j < 2; j++) {
      bfr[j][0] = *(const bf16x8*)(smc + b3Off + j * 1024u + px0);
      bfr[j][1] = *(const bf16x8*)(smc + b3Off + j * 1024u + px1);
    }
    STG2(smn, 16384u, pB10, pB11, kn);
    __builtin_amdgcn_s_barrier();
    __builtin_amdgcn_sched_barrier(0);
    __builtin_amdgcn_s_setprio(1);
#pragma unroll
    for (int ti = 0; ti < 4; ti++)
#pragma unroll
      for (int j = 0; j < 2; j++) {
        acc3[ti][j] = __builtin_amdgcn_mfma_f32_16x16x32_bf16(af[ti][0], bfr[j][0], acc3[ti][j], 0, 0, 0);
        acc3[ti][j] = __builtin_amdgcn_mfma_f32_16x16x32_bf16(af[ti][1], bfr[j][1], acc3[ti][j], 0, 0, 0);
      }
    __builtin_amdgcn_s_setprio(0);

    // -- phase 3: read B3[tj23]; stage next B3; vmcnt(2); MFMA acc3 tj23 ----
#pragma unroll
    for (int j = 0; j < 2; j++) {
      bfr[j][0] = *(const bf16x8*)(smc + b3Off + 2048u + j * 1024u + px0);
      bfr[j][1] = *(const bf16x8*)(smc + b3Off + 2048u + j * 1024u + px1);
    }
    STG2(smn, 24576u, pB30, pB31, kn);
    asm volatile("s_waitcnt vmcnt(2)" ::: "memory");
    __builtin_amdgcn_s_barrier();
    __builtin_amdgcn_sched_barrier(0);
    __builtin_amdgcn_s_setprio(1);
#pragma unroll
    for (int ti = 0; ti < 4; ti++)
#pragma unroll
      for (int j = 0; j < 2; j++) {
        acc3[ti][2 + j] = __builtin_amdgcn_mfma_f32_16x16x32_bf16(af[ti][0], bfr[j][0], acc3[ti][2 + j], 0, 0, 0);
        acc3[ti][2 + j] = __builtin_amdgcn_mfma_f32_16x16x32_bf16(af[ti][1], bfr[j][1], acc3[ti][2 + j], 0, 0, 0);
      }
    __builtin_amdgcn_s_setprio(0);
  }
  asm volatile("s_waitcnt vmcnt(0)" ::: "memory");

  // epilogue: weighted atomic scatter (acc1 -> cols n0+wc*64.., acc3 -> +128)
#pragma unroll
  for (int ti = 0; ti < 4; ti++)
#pragma unroll
    for (int r = 0; r < 4; r++) {
      int lrow = wr * 64 + ti * 16 + q * 4 + r;
      float wt = wts[lrow];
      if (wt != 0.f) {
        int trow = toks[lrow];
#pragma unroll
        for (int tj = 0; tj < 4; tj++) {
          int gcol = n0 + wc * 64 + tj * 16 + lm;
          atomicAdd(&out[(size_t)trow * HID + gcol],       acc1[ti][tj][r] * wt);
          atomicAdd(&out[(size_t)trow * HID + gcol + 128], acc3[ti][tj][r] * wt);
        }
      }
    }
}

// ---------------------------------------------------------------------------
extern "C" void kernel_launch(void* const* d_in, const int* in_sizes, int n_in,
                              void* d_out, int out_size, void* d_ws, size_t ws_size,
                              hipStream_t stream) {
  const float* x  = (const float*)d_in[0];
  const float* gw = (const float*)d_in[1];
  const float* gb = (const float*)d_in[2];
  const float* w1 = (const float*)d_in[3];
  const float* w3 = (const float*)d_in[4];
  const float* w2 = (const float*)d_in[5];
  float* out = (float*)d_out;

  char* ws = (char*)d_ws;
  int*   counts     = (int*)(ws + 0);        // 8
  int*   fill       = (int*)(ws + 32);       // 8
  int*   offs       = (int*)(ws + 64);       // 8
  int*   t128_e     = (int*)(ws + 96);       // 80 (legacy, unused by GEMMs)
  int*   t128_row   = (int*)(ws + 416);      // 80
  int*   t256_e     = (int*)(ws + 736);      // 40
  int*   t256_row   = (int*)(ws + 896);      // 40  (ends 1056)
  int*   topi       = (int*)(ws + 2048);     // 8192 ints  -> 34816
  float* topw       = (float*)(ws + 34816);  // 8192 f     -> 67584
  int*   sorted_tok = (int*)(ws + 67584);    // CAP ints   -> 108544
  float* sorted_w   = (float*)(ws + 108544); // CAP f      -> 149504
  unsigned short* xbf = (unsigned short*)(ws + 149504); // 8MB -> 8538112
  const size_t base = 8538112ull;

  int FC = FFN;
  while (FC > 128) {
    size_t W  = (size_t)NE * FC * HID * 2;
    size_t Hb = (size_t)CAP * FC * 2;
    if (base + 3 * W + Hb <= ws_size) break;
    FC >>= 1;
  }
  size_t W = (size_t)NE * FC * HID * 2;
  unsigned short* w1t  = (unsigned short*)(ws + base);
  unsigned short* w3t  = (unsigned short*)(ws + base + W);
  unsigned short* w2t  = (unsigned short*)(ws + base + 2 * W);
  unsigned short* hbuf = (unsigned short*)(ws + base + 3 * W);
  int nc = FFN / FC;

  static bool attr_set = false;
  if (!attr_set) {
    hipFuncSetAttribute((const void*)k5_gemm_h8<4096>, hipFuncAttributeMaxDynamicSharedMemorySize, 131072);
    hipFuncSetAttribute((const void*)k5_gemm_h8<2048>, hipFuncAttributeMaxDynamicSharedMemorySize, 131072);
    hipFuncSetAttribute((const void*)k5_gemm_h8<1024>, hipFuncAttributeMaxDynamicSharedMemorySize, 131072);
    hipFuncSetAttribute((const void*)k5_gemm_h8<0>,    hipFuncAttributeMaxDynamicSharedMemorySize, 131072);
    hipFuncSetAttribute((const void*)k6_gemm_o8<4096>, hipFuncAttributeMaxDynamicSharedMemorySize, 131072);
    hipFuncSetAttribute((const void*)k6_gemm_o8<2048>, hipFuncAttributeMaxDynamicSharedMemorySize, 131072);
    hipFuncSetAttribute((const void*)k6_gemm_o8<1024>, hipFuncAttributeMaxDynamicSharedMemorySize, 131072);
    hipFuncSetAttribute((const void*)k6_gemm_o8<0>,    hipFuncAttributeMaxDynamicSharedMemorySize, 131072);
    attr_set = true;
  }

  k0_zero_cvt<<<4096, 256, 0, stream>>>(x, xbf, out, counts);
  k2_router<<<1024, 256, 0, stream>>>(x, gw, gb, topi, topw, counts);
  k3_scan<<<1, 256, 0, stream>>>(counts, offs, fill, t128_e, t128_row,
                                 t256_e, t256_row, sorted_tok, sorted_w);
  k4_scatter<<<16, 256, 0, stream>>>(topi, topw, offs, fill, sorted_tok, sorted_w);

  for (int c = 0; c < nc; c++) {
    int c0 = c * FC;
    // w1/w3 [e][HID][FFN] cols chunk -> [e][FC][HID] (fused, grid.z=16)
    k1_transpose<<<dim3(FC / 64, HID / 64, 16), 256, 0, stream>>>(
        w1, w1t, w3, w3t, HID, FFN, 0, c0, HID, FC);
    // w2 [e][FFN][HID] rows chunk -> [e][HID][FC]
    k1_transpose<<<dim3(HID / 64, FC / 64, 8), 256, 0, stream>>>(
        w2, w2t, nullptr, nullptr, FFN, HID, c0, 0, FC, HID);
    dim3 g5(MAXT256 * (FC / 128));
    dim3 g6(MAXT256 * (HID / 256));
    if (FC == 4096) {
      k5_gemm_h8<4096><<<g5, 512, 131072, stream>>>(
          xbf, w1t, w3t, hbuf, t256_e, t256_row, sorted_tok, FC);
      k6_gemm_o8<4096><<<g6, 512, 131072, stream>>>(
          hbuf, w2t, out, t256_e, t256_row, sorted_tok, sorted_w, FC);
    } else if (FC == 2048) {
      k5_gemm_h8<2048><<<g5, 512, 131072, stream>>>(
          xbf, w1t, w3t, hbuf, t256_e, t256_row, sorted_tok, FC);
      k6_gemm_o8<2048><<<g6, 512, 131072, stream>>>(
          hbuf, w2t, out, t256_e, t256_row, sorted_tok, sorted_w, FC);
    } else if (FC == 1024) {
      k5_gemm_h8<1024><<<g5, 512, 131072, stream>>>(
          xbf, w1t, w3t, hbuf, t256_e, t256_row, sorted_tok, FC);
      k6_gemm_o8<1024><<<g6, 512, 131072, stream>>>(
          hbuf, w2t, out, t256_e, t256_row, sorted_tok, sorted_w, FC);
    } else {
      k5_gemm_h8<0><<<g5, 512, 131072, stream>>>(
          xbf, w1t, w3t, hbuf, t256_e, t256_row, sorted_tok, FC);
      k6_gemm_o8<0><<<g6, 512, 131072, stream>>>(
          hbuf, w2t, out, t256_e, t256_row, sorted_tok, sorted_w, FC);
    }
  }
}